// Round 10
// baseline (1972.513 us; speedup 1.0000x reference)
//
#include <hip/hip_runtime.h>
#include <hip/hip_bf16.h>
#include <stdint.h>

// Problem constants (fixed by setup_inputs)
#define BB 8
#define NN 16384
#define GG 1024
#define SS 32
#define BN (BB*NN)          // 131072

// Output offsets (elements, float32)
#define OFF_SIDX 0
#define OFF_SN   8192
#define OFF_SXYZ 770048     // 8192 + 8192*31*3
#define OFF_ORD  794624     // + 24576
#define OFF_INV  827392     // + 32768

// Workspace offsets (bytes)
#define WS_SIDX 0                    // int[8192]
#define WS_KNN  32768                // int[8192*32] = 1 MB

typedef float v2f __attribute__((ext_vector_type(2)));
typedef unsigned long long u64x2 __attribute__((ext_vector_type(2)));

static __device__ __forceinline__ v2f vmin2(v2f a, v2f b) {
    v2f r; r.x = fminf(a.x, b.x); r.y = fminf(a.y, b.y); return r;
}
static __device__ __forceinline__ v2f vmax2(v2f a, v2f b) {
    v2f r; r.x = fmaxf(a.x, b.x); r.y = fmaxf(a.y, b.y); return r;
}

// DPP u32 max merge (fuses to v_max_u32_dpp). old=v, bound_ctrl=false =>
// lanes without a valid source keep v (idempotent merge).
template<int CTRL, int RM, int BM>
static __device__ __forceinline__ unsigned dpp_umax(unsigned v) {
    unsigned o = (unsigned)__builtin_amdgcn_update_dpp((int)v, (int)v, CTRL, RM, BM, false);
    return o > v ? o : v;
}

// DPP u64 min merge.
template<int CTRL, int RM, int BM>
static __device__ __forceinline__ uint64_t dpp_umin64(uint64_t v) {
    unsigned lo = (unsigned)v, hi = (unsigned)(v >> 32);
    unsigned olo = (unsigned)__builtin_amdgcn_update_dpp((int)lo, (int)lo, CTRL, RM, BM, false);
    unsigned ohi = (unsigned)__builtin_amdgcn_update_dpp((int)hi, (int)hi, CTRL, RM, BM, false);
    uint64_t o = ((uint64_t)ohi << 32) | olo;
    return o < v ? o : v;
}

// full-wave u64 min, result valid in lane 63
static __device__ __forceinline__ uint64_t wave_umin64(uint64_t v) {
    v = dpp_umin64<0x111, 0xf, 0xf>(v);   // row_shr:1
    v = dpp_umin64<0x112, 0xf, 0xf>(v);   // row_shr:2
    v = dpp_umin64<0x114, 0xf, 0xf>(v);   // row_shr:4
    v = dpp_umin64<0x118, 0xf, 0xf>(v);   // row_shr:8
    v = dpp_umin64<0x142, 0xa, 0xf>(v);   // row_bcast:15 -> rows 1,3
    v = dpp_umin64<0x143, 0xc, 0xf>(v);   // row_bcast:31 -> rows 2,3
    return v;
}

// broadcast u64 from (uniform) lane sl
static __device__ __forceinline__ uint64_t rdlane64(uint64_t v, int sl) {
    unsigned lo = (unsigned)__builtin_amdgcn_readlane((int)(unsigned)v, sl);
    unsigned hi = (unsigned)__builtin_amdgcn_readlane((int)(unsigned)(v >> 32), sl);
    return ((uint64_t)hi << 32) | lo;
}

// Monotone float->u32 map: preserves IEEE float ordering even for negatives
// (d2 = (cc+pp)-2dot can round to tiny negatives; numpy orders them lowest).
static __device__ __forceinline__ unsigned mono(float f) {
    unsigned u = __float_as_uint(f);
    return u ^ (unsigned)((((int)u) >> 31) | (int)0x80000000u);
}

// ---------------------------------------------------------------------------
// 1) FPS: one block/batch, 1024 thr, 16 contiguous pts/thread (p = t*16+j).
//    R24: PACKED-F32 UPDATE (inline-asm v_pk_add/mul) + fused max.
//    Evidence: R1 (L1 refetch), R6 (LDS @2w), R9 (LDS @4w, NO spill,
//    VGPR=52) all land at 1.47-1.66 us/step -> the memory medium is NOT the
//    bottleneck. R9 PMC: VALUBusy 66% of active CUs = ~2370 cyc/SIMD/step of
//    VALU issue -> compiler emits SCALAR f32 ops (~20/pair). gfx950 VOP3P
//    v_pk_{add,mul}_f32 does 2 lanes' worth/inst. Update loop rewritten:
//    3 pk_add (sub via pre-negated q: x+(-y) == x-y bit-exact) + 3 in-place
//    pk_mul squares + 2 pk_add in ref order (dx^2+dy^2)+dz^2 + scalar
//    min/max = 12 inst/pair vs ~20. Max-tree fused into the update loop
//    (mx accumulator) -> serial head of each step starts at the DPP reduce.
//    Everything else (LDS xy layout, z+dist in regs, claim path, barriers)
//    = R9-validated, byte-identical.
//    TELL: success <=> fps ~1.15-1.3ms & VALUBusy(active) drops toward ~50%.
//    If dur unchanged -> serial chain is the floor; attack barriers next.
// ---------------------------------------------------------------------------
__global__ __launch_bounds__(1024)
void fps_kernel(const float* __restrict__ coord,
                int* __restrict__ ws_sidx,
                float* __restrict__ out) {
#pragma clang fp contract(off)
    const int b = blockIdx.x;
    const int t = threadIdx.x;
    const int base = b * NN;
    const int wave = t >> 6, lane = t & 63;

    // 128 KB: per-thread private x/y pair slots (column layout: lane-adjacent)
    __shared__ __align__(16) v2f lds_xp[8192];   // [j*1024 + t]
    __shared__ __align__(16) v2f lds_yp[8192];
    __shared__ unsigned wv[16];       // per-wave max bits
    __shared__ unsigned win[2];       // packed winner p, double-buffered

    // q0 = pts[0] (uniform scalar load)
    const float q0x = coord[3*base], q0y = coord[3*base+1], q0z = coord[3*base+2];

    // thread-local flat view of my 48 floats (points t*16 .. t*16+15)
    const float* my = coord + 3*(base + t*16);

    // one-time load: pair j holds points 2j (x-slot) and 2j+1 (y-slot).
    // x,y -> my private LDS slots; z pinned in registers.
    // Init dist vs q0 with the same packed sequence used in the loop
    // (order (dx*dx + dy*dy) + dz*dz, contract off -> bit-exact vs ref).
    v2f pz[8], dist[8];
    v2f mx = (v2f){-__builtin_inff(), -__builtin_inff()};
    {
        v2f nq0x = (v2f){-q0x, -q0x}, nq0y = (v2f){-q0y, -q0y}, nq0z = (v2f){-q0z, -q0z};
#pragma unroll
        for (int j = 0; j < 8; j++) {
            v2f px = (v2f){my[6*j  ], my[6*j+3]};
            v2f py = (v2f){my[6*j+1], my[6*j+4]};
            pz[j]  = (v2f){my[6*j+2], my[6*j+5]};
            lds_xp[(j<<10) + t] = px;
            lds_yp[(j<<10) + t] = py;
            v2f dx, dy, dz, sxy, s;
            asm("v_pk_add_f32 %0, %1, %2" : "=v"(dx) : "v"(px),    "v"(nq0x));
            asm("v_pk_add_f32 %0, %1, %2" : "=v"(dy) : "v"(py),    "v"(nq0y));
            asm("v_pk_add_f32 %0, %1, %2" : "=v"(dz) : "v"(pz[j]), "v"(nq0z));
            asm("v_pk_mul_f32 %0, %0, %0" : "+v"(dx));
            asm("v_pk_mul_f32 %0, %0, %0" : "+v"(dy));
            asm("v_pk_mul_f32 %0, %0, %0" : "+v"(dz));
            asm("v_pk_add_f32 %0, %1, %2" : "=v"(sxy) : "v"(dx), "v"(dy));
            asm("v_pk_add_f32 %0, %1, %2" : "=v"(s)   : "v"(sxy), "v"(dz));
            dist[j] = s;                      // == min(inf, d2)
            mx = vmax2(mx, dist[j]);
        }
    }
#pragma unroll
    for (int j = 0; j < 8; j++) asm volatile("" : "+v"(pz[j]));

    if (t == 0) {
        ws_sidx[b*GG] = base;                 // selection 0 = index 0
        out[OFF_SIDX + b*GG] = (float)base;
        win[0] = 0xffffffffu; win[1] = 0xffffffffu;
    }
    __syncthreads();

    for (int g = 1; g < GG; g++) {
        const int s = g & 1;
        // ---- per-thread max already fused into previous update (mx)
        float bvf = fmaxf(mx.x, mx.y);
        unsigned lb = __float_as_uint(bvf);   // local max as orderable bits
        // ---- wave max via DPP (value only; result in lane 63)
        unsigned r = lb;
        r = dpp_umax<0x111, 0xf, 0xf>(r);
        r = dpp_umax<0x112, 0xf, 0xf>(r);
        r = dpp_umax<0x114, 0xf, 0xf>(r);
        r = dpp_umax<0x118, 0xf, 0xf>(r);
        r = dpp_umax<0x142, 0xa, 0xf>(r);
        r = dpp_umax<0x143, 0xc, 0xf>(r);
        unsigned wmax = (unsigned)__builtin_amdgcn_readlane((int)r, 63);
        if (lane == 0) wv[wave] = wmax;
        __syncthreads();                      // B1
        if (t == 0) win[1 - s] = 0xffffffffu; // reset other slot for step g+1
        // ---- block max: 16 wave winners, 4-level DPP within rows of 16
        unsigned x = wv[lane & 15];
        x = dpp_umax<0x111, 0xf, 0xf>(x);
        x = dpp_umax<0x112, 0xf, 0xf>(x);
        x = dpp_umax<0x114, 0xf, 0xf>(x);
        x = dpp_umax<0x118, 0xf, 0xf>(x);
        unsigned bmax = (unsigned)__builtin_amdgcn_readlane((int)x, 15);
        // ---- claim: exact first-max index = min p = t*16 + jj (rare path)
        if (lb == bmax) {
            int e = 15;
#pragma unroll
            for (int jj = 15; jj >= 0; jj--) {
                float v = (jj & 1) ? dist[jj >> 1].y : dist[jj >> 1].x;
                if (__float_as_uint(v) == bmax) e = jj;
            }
            atomicMin(&win[s], (unsigned)(t*16 + e));
        }
        __syncthreads();                      // B2: winner resolved
        unsigned pw = win[s];
        int sp = __builtin_amdgcn_readfirstlane((int)pw);
        if (t == 0) {
            ws_sidx[b*GG + g] = base + sp;
            out[OFF_SIDX + b*GG + g] = (float)(base + sp);
        }
        // uniform (scalar) load of winner coords
        float qx = coord[3*(base+sp)];
        float qy = coord[3*(base+sp)+1];
        float qz = coord[3*(base+sp)+2];
        // ---- update: dist = min(dist, |p - q_g|^2), bit-exact, PACKED.
        //      x+(-q) == x-q exactly (IEEE); squares+sums in ref order;
        //      x,y stream from private LDS slots; z from registers.
        v2f nqx = (v2f){-qx, -qx}, nqy = (v2f){-qy, -qy}, nqz = (v2f){-qz, -qz};
        mx = (v2f){-__builtin_inff(), -__builtin_inff()};
#pragma unroll
        for (int j = 0; j < 8; j++) {
            v2f px = lds_xp[(j<<10) + t];
            v2f py = lds_yp[(j<<10) + t];
            v2f dx, dy, dz, sxy, d;
            asm("v_pk_add_f32 %0, %1, %2" : "=v"(dx) : "v"(px),    "v"(nqx));
            asm("v_pk_add_f32 %0, %1, %2" : "=v"(dy) : "v"(py),    "v"(nqy));
            asm("v_pk_add_f32 %0, %1, %2" : "=v"(dz) : "v"(pz[j]), "v"(nqz));
            asm("v_pk_mul_f32 %0, %0, %0" : "+v"(dx));
            asm("v_pk_mul_f32 %0, %0, %0" : "+v"(dy));
            asm("v_pk_mul_f32 %0, %0, %0" : "+v"(dz));
            asm("v_pk_add_f32 %0, %1, %2" : "=v"(sxy) : "v"(dx), "v"(dy));
            asm("v_pk_add_f32 %0, %1, %2" : "=v"(d)   : "v"(sxy), "v"(dz));
            dist[j] = vmin2(dist[j], d);
            mx = vmax2(mx, dist[j]);
        }
    }
}

// ---------------------------------------------------------------------------
// 2) kNN top-32: one wave per center, no LDS. Per-lane TOP-2 cache of packed
//    keys (mono(d2)<<14 | p): the scattered rescan of the winner's stripe
//    runs only when the winner's cache is empty (~7/32 rounds). mono() makes
//    key order == (d2 float order, index) lex == stable top_k semantics.
// ---------------------------------------------------------------------------
__global__ __launch_bounds__(64) void knn_kernel(const float* __restrict__ coord,
                                                 const int* __restrict__ ws_sidx,
                                                 int* __restrict__ ws_knn) {
#pragma clang fp contract(off)
    const int c = blockIdx.x;             // center 0..8191
    const int l = threadIdx.x;            // lane 0..63
    const int b = c >> 10;
    const int base = b * NN;
    const int sg = ws_sidx[c];            // global center index
    const float cx = coord[3*sg], cy = coord[3*sg+1], cz = coord[3*sg+2];
    const float cc = (cx*cx + cy*cy) + cz*cz;

    // phase 1: per-lane two smallest keys over stripe {l + 64*j}
    uint64_t k1 = ~0ull, k2 = ~0ull;
#pragma unroll 4
    for (int j = 0; j < 256; j++) {
        int p = l + (j << 6);
        float x = coord[3*(base+p)], y = coord[3*(base+p)+1], z = coord[3*(base+p)+2];
        float pp  = (x*x + y*y) + z*z;
        float dot = (cx*x + cy*y) + cz*z;
        float d2  = (cc + pp) - 2.0f*dot;             // ref formula exactly
        uint64_t key = (((uint64_t)mono(d2)) << 14) | (unsigned)p;
        if (key < k1)      { k2 = k1; k1 = key; }
        else if (key < k2) { k2 = key; }
    }

    uint64_t m0 = 0, m1 = 0, m2 = 0, m3 = 0;          // consumed bits, my stripe
    uint64_t cur = k1, nxt = k2;
    bool have_nxt = true;
    int res_p = 0;
    for (int k = 0; k < SS; k++) {
        // global argmin over per-lane current minima (value, then index)
        uint64_t wmin = wave_umin64(cur);
        uint64_t bkey = rdlane64(wmin, 63);           // scalar winner key
        const int bp = (int)(bkey & 16383u);          // winner point (scalar)
        const int w  = bp & 63;                       // winner lane / stripe
        const int e  = bp >> 6;                       // element within stripe
        if (l == k) res_p = bp;                       // lane k keeps k-th neighbor
        bool need_rescan = false;
        if (l == w) {                                 // mark consumed
            uint64_t bit = 1ull << (e & 63);
            int word = e >> 6;
            if      (word == 0) m0 |= bit;
            else if (word == 1) m1 |= bit;
            else if (word == 2) m2 |= bit;
            else                m3 |= bit;
            if (have_nxt) { cur = nxt; have_nxt = false; }
            else need_rescan = true;
        }
        if (__ballot(need_rescan)) {                  // wave-uniform rare path
            uint64_t w0 = rdlane64(m0, w), w1 = rdlane64(m1, w),
                     w2 = rdlane64(m2, w), w3 = rdlane64(m3, w);
            uint64_t best = ~0ull;
#pragma unroll
            for (int m = 0; m < 4; m++) {
                int e2 = l + (m << 6);
                uint64_t mw = (m == 0) ? w0 : ((m == 1) ? w1 : ((m == 2) ? w2 : w3));
                int p2 = w + (e2 << 6);
                float x = coord[3*(base+p2)], y = coord[3*(base+p2)+1], z = coord[3*(base+p2)+2];
                float pp  = (x*x + y*y) + z*z;
                float dot = (cx*x + cy*y) + cz*z;
                float d2  = (cc + pp) - 2.0f*dot;     // bit-exact recompute
                uint64_t key = (((uint64_t)mono(d2)) << 14) | (unsigned)p2;
                bool cons = (mw >> l) & 1ull;
                if (!cons && key < best) best = key;
            }
            best = wave_umin64(best);
            uint64_t rk = rdlane64(best, 63);
            if (l == w) cur = rk;                     // refreshed stripe-min
        }
    }
    if (l < SS) ws_knn[c * SS + l] = res_p;           // local point index
}

// ---------------------------------------------------------------------------
// 3) s_xyz gather
// ---------------------------------------------------------------------------
__global__ void sxyz_kernel(const float* __restrict__ coord,
                            const int* __restrict__ ws_sidx,
                            float* __restrict__ out) {
    int t = blockIdx.x * blockDim.x + threadIdx.x;
    if (t < 8192*3) {
        int i = t / 3, cmp = t - 3*i;
        out[OFF_SXYZ + t] = coord[3*ws_sidx[i] + cmp];
    }
}

// ---------------------------------------------------------------------------
// 4) s_n = coord[knn[1..31]] - center
// ---------------------------------------------------------------------------
__global__ void sn_kernel(const float* __restrict__ coord,
                          const int* __restrict__ ws_sidx,
                          const int* __restrict__ ws_knn,
                          float* __restrict__ out) {
#pragma clang fp contract(off)
    int t = blockIdx.x * blockDim.x + threadIdx.x;
    if (t < 8192*31*3) {
        int cmp = t % 3; int rem = t / 3;
        int j = rem % 31; int i = rem / 31;
        int b = i >> 10;
        int nb = ws_knn[i*SS + j + 1];                // skip neighbor 0 (self)
        int gidx = b*NN + nb;
        float v = coord[3*gidx + cmp] - coord[3*ws_sidx[i] + cmp];
        out[OFF_SN + t] = v;
    }
}

// ---------------------------------------------------------------------------
// 5) stable argsort per code row: REGISTER-BLOCKED bitonic sort of
//    (code<<13 | idx). Thread t owns the 8 contiguous elements i=8t..8t+7 in
//    registers; j>=8 passes swap 64B blocks via LDS. Unique keys => total
//    order == stable argsort (exact).
// ---------------------------------------------------------------------------
__global__ __launch_bounds__(1024) void sort_kernel(const int* __restrict__ ser,
                                                    const int* __restrict__ ws_sidx,
                                                    float* __restrict__ out) {
    __shared__ __align__(16) uint64_t keys[8192];     // 64 KB
    const int r = blockIdx.x, t = threadIdx.x;
    uint64_t e[8];
#pragma unroll
    for (int m = 0; m < 8; m++) {
        int i = t*8 + m;
        uint32_t code = (uint32_t)ser[r * BN + ws_sidx[i]];   // < 2^30
        e[m] = ((uint64_t)code << 13) | (uint32_t)i;          // unique keys
    }
#define CE(a, b, up) { uint64_t xa = e[a], xb = e[b]; \
                       if ((xa > xb) == (up)) { e[a] = xb; e[b] = xa; } }
    // k2 = 2 (up = ((m&2)==0)):
    CE(0,1,true) CE(2,3,false) CE(4,5,true) CE(6,7,false)
    // k2 = 4 (up = ((m&4)==0)):
    CE(0,2,true) CE(1,3,true) CE(4,6,false) CE(5,7,false)
    CE(0,1,true) CE(2,3,true) CE(4,5,false) CE(6,7,false)
    // k2 = 8 (up = ((t&1)==0), uniform in thread):
    {
        bool up = ((t & 1) == 0);
        CE(0,4,up) CE(1,5,up) CE(2,6,up) CE(3,7,up)
        CE(0,2,up) CE(1,3,up) CE(4,6,up) CE(5,7,up)
        CE(0,1,up) CE(2,3,up) CE(4,5,up) CE(6,7,up)
    }
    u64x2* kp = (u64x2*)keys;
    for (int k2 = 16; k2 <= 8192; k2 <<= 1) {
        const bool up = ((t & (k2 >> 3)) == 0);
        for (int j = k2 >> 1; j >= 8; j >>= 1) {
            // publish my current block
#pragma unroll
            for (int q = 0; q < 4; q++)
                kp[t*4 + q] = (u64x2){e[2*q], e[2*q+1]};
            __syncthreads();
            // read partner block (element m pairs with partner's element m)
            const int pt = t ^ (j >> 3);
            uint64_t pb[8];
#pragma unroll
            for (int q = 0; q < 4; q++) {
                u64x2 v = kp[pt*4 + q];
                pb[2*q] = v.x; pb[2*q+1] = v.y;
            }
            const bool lower = ((t & (j >> 3)) == 0);
            const bool keepmin = (lower == up);
#pragma unroll
            for (int m = 0; m < 8; m++) {
                uint64_t a = e[m], bq = pb[m];
                uint64_t mn = a < bq ? a : bq;
                uint64_t mx = a < bq ? bq : a;
                e[m] = keepmin ? mn : mx;
            }
            __syncthreads();   // all reads done before next pass overwrites
        }
        // tail j = 4, 2, 1 in-register (direction up, uniform)
        CE(0,4,up) CE(1,5,up) CE(2,6,up) CE(3,7,up)
        CE(0,2,up) CE(1,3,up) CE(4,6,up) CE(5,7,up)
        CE(0,1,up) CE(2,3,up) CE(4,5,up) CE(6,7,up)
    }
#undef CE
#pragma unroll
    for (int m = 0; m < 8; m++) {
        int k = t*8 + m;
        uint64_t key = e[m];
        int i = (int)(key & 8191u);
        out[OFF_ORD + r*8192 + k] = (float)i;
        out[OFF_INV + r*8192 + i] = (float)k;
    }
}

// ---------------------------------------------------------------------------
extern "C" void kernel_launch(void* const* d_in, const int* in_sizes, int n_in,
                              void* d_out, int out_size, void* d_ws, size_t ws_size,
                              hipStream_t stream) {
    const float* coord = (const float*)d_in[0];
    const int* ser = (const int*)d_in[1];
    float* out = (float*)d_out;
    char* ws = (char*)d_ws;
    int* ws_sidx = (int*)(ws + WS_SIDX);
    int* ws_knn  = (int*)(ws + WS_KNN);

    hipLaunchKernelGGL(fps_kernel,  dim3(BB),   dim3(1024), 0, stream, coord, ws_sidx, out);
    hipLaunchKernelGGL(knn_kernel,  dim3(8192), dim3(64),   0, stream, coord, ws_sidx, ws_knn);
    hipLaunchKernelGGL(sxyz_kernel, dim3(96),   dim3(256),  0, stream, coord, ws_sidx, out);
    hipLaunchKernelGGL(sn_kernel,   dim3(2976), dim3(256),  0, stream, coord, ws_sidx, ws_knn, out);
    hipLaunchKernelGGL(sort_kernel, dim3(4),    dim3(1024), 0, stream, ser, ws_sidx, out);
}

// Round 11
// 1963.131 us; speedup vs baseline: 1.0048x; 1.0048x over previous
//
#include <hip/hip_runtime.h>
#include <hip/hip_bf16.h>
#include <stdint.h>

// Problem constants (fixed by setup_inputs)
#define BB 8
#define NN 16384
#define GG 1024
#define SS 32
#define BN (BB*NN)          // 131072

// Output offsets (elements, float32)
#define OFF_SIDX 0
#define OFF_SN   8192
#define OFF_SXYZ 770048     // 8192 + 8192*31*3
#define OFF_ORD  794624     // + 24576
#define OFF_INV  827392     // + 32768

// Workspace offsets (bytes)
#define WS_SIDX 0                    // int[8192]
#define WS_KNN  32768                // int[8192*32] = 1 MB

typedef float v2f __attribute__((ext_vector_type(2)));
typedef unsigned long long u64x2 __attribute__((ext_vector_type(2)));

static __device__ __forceinline__ v2f vmin2(v2f a, v2f b) {
    v2f r; r.x = fminf(a.x, b.x); r.y = fminf(a.y, b.y); return r;
}
static __device__ __forceinline__ v2f vmax2(v2f a, v2f b) {
    v2f r; r.x = fmaxf(a.x, b.x); r.y = fmaxf(a.y, b.y); return r;
}

// Packed |p-q|^2 in ref order: (dx*dx + dy*dy) + dz*dz, sub as add of
// pre-negated q (bit-exact IEEE). ONE asm block, early-clobber temps, no
// tied operands -> no allocator copy chains (R10 lesson). Packed semantics
// HW-verified bit-exact in R10 (passed, same absmax).
static __device__ __forceinline__ v2f pk_d2(v2f px, v2f py, v2f pz,
                                            v2f nqx, v2f nqy, v2f nqz) {
    v2f d, t1, t2;
    asm("v_pk_add_f32 %0, %3, %6\n\t"
        "v_pk_add_f32 %1, %4, %7\n\t"
        "v_pk_add_f32 %2, %5, %8\n\t"
        "v_pk_mul_f32 %0, %0, %0\n\t"
        "v_pk_mul_f32 %1, %1, %1\n\t"
        "v_pk_mul_f32 %2, %2, %2\n\t"
        "v_pk_add_f32 %0, %0, %1\n\t"
        "v_pk_add_f32 %0, %0, %2"
        : "=&v"(d), "=&v"(t1), "=&v"(t2)
        : "v"(px), "v"(py), "v"(pz), "v"(nqx), "v"(nqy), "v"(nqz));
    return d;
}

// DPP u32 max merge (fuses to v_max_u32_dpp). old=v, bound_ctrl=false =>
// lanes without a valid source keep v (idempotent merge).
template<int CTRL, int RM, int BM>
static __device__ __forceinline__ unsigned dpp_umax(unsigned v) {
    unsigned o = (unsigned)__builtin_amdgcn_update_dpp((int)v, (int)v, CTRL, RM, BM, false);
    return o > v ? o : v;
}

// DPP u64 min merge.
template<int CTRL, int RM, int BM>
static __device__ __forceinline__ uint64_t dpp_umin64(uint64_t v) {
    unsigned lo = (unsigned)v, hi = (unsigned)(v >> 32);
    unsigned olo = (unsigned)__builtin_amdgcn_update_dpp((int)lo, (int)lo, CTRL, RM, BM, false);
    unsigned ohi = (unsigned)__builtin_amdgcn_update_dpp((int)hi, (int)hi, CTRL, RM, BM, false);
    uint64_t o = ((uint64_t)ohi << 32) | olo;
    return o < v ? o : v;
}

// full-wave u64 min, result valid in lane 63
static __device__ __forceinline__ uint64_t wave_umin64(uint64_t v) {
    v = dpp_umin64<0x111, 0xf, 0xf>(v);   // row_shr:1
    v = dpp_umin64<0x112, 0xf, 0xf>(v);   // row_shr:2
    v = dpp_umin64<0x114, 0xf, 0xf>(v);   // row_shr:4
    v = dpp_umin64<0x118, 0xf, 0xf>(v);   // row_shr:8
    v = dpp_umin64<0x142, 0xa, 0xf>(v);   // row_bcast:15 -> rows 1,3
    v = dpp_umin64<0x143, 0xc, 0xf>(v);   // row_bcast:31 -> rows 2,3
    return v;
}

// broadcast u64 from (uniform) lane sl
static __device__ __forceinline__ uint64_t rdlane64(uint64_t v, int sl) {
    unsigned lo = (unsigned)__builtin_amdgcn_readlane((int)(unsigned)v, sl);
    unsigned hi = (unsigned)__builtin_amdgcn_readlane((int)(unsigned)(v >> 32), sl);
    return ((uint64_t)hi << 32) | lo;
}

// Monotone float->u32 map: preserves IEEE float ordering even for negatives
// (d2 = (cc+pp)-2dot can round to tiny negatives; numpy orders them lowest).
static __device__ __forceinline__ unsigned mono(float f) {
    unsigned u = __float_as_uint(f);
    return u ^ (unsigned)((((int)u) >> 31) | (int)0x80000000u);
}

// ---------------------------------------------------------------------------
// 1) FPS: one block/batch, 1024 thr, 16 contiguous pts/thread (p = t*16+j).
//    R25: R9 base (x,y in LDS private slots, z+dist in regs, 4 waves/SIMD)
//    + CLEAN packed-f32 arithmetic (single asm block/pair, "=&v" temps).
//    Consolidated model over R1-R10 (all consistent):
//      R1 global: TCP floor 3100cyc = 1.47us  [memory-floored]
//      R9 LDS@4w: VALU floor 2376cyc = 1.51us [scalar f32, ~22 iss/pair]
//      R10 per-op tied asm: copies kept VALU ~2500 = 1.64us
//    Packing pays ONLY on the LDS base (memory already off critical path).
//    Per pair now: 8 v_pk (one block, no ties -> no copies) + 4 scalar
//    min/max on halves = ~12 issues vs 22. Predicted VALU ~1250 cyc/SIMD;
//    step ~ max(1250, LDS 1000) + serial ~1000 ~ 2300cyc ~ 0.96us.
//    Claim path / reduce / barriers = R9-validated, byte-identical.
//    TELL: fps ~950-1150us & VALUBusy ~1.3-1.6% device. If VALU drops but
//    time doesn't -> serial chain is the floor (declare next round).
// ---------------------------------------------------------------------------
__global__ __launch_bounds__(1024)
void fps_kernel(const float* __restrict__ coord,
                int* __restrict__ ws_sidx,
                float* __restrict__ out) {
#pragma clang fp contract(off)
    const int b = blockIdx.x;
    const int t = threadIdx.x;
    const int base = b * NN;
    const int wave = t >> 6, lane = t & 63;

    // 128 KB: per-thread private x/y pair slots (column layout: lane-adjacent)
    __shared__ __align__(16) v2f lds_xp[8192];   // [j*1024 + t]
    __shared__ __align__(16) v2f lds_yp[8192];
    __shared__ unsigned wv[16];       // per-wave max bits
    __shared__ unsigned win[2];       // packed winner p, double-buffered

    // q0 = pts[0] (uniform scalar load)
    const float q0x = coord[3*base], q0y = coord[3*base+1], q0z = coord[3*base+2];

    // thread-local flat view of my 48 floats (points t*16 .. t*16+15)
    const float* my = coord + 3*(base + t*16);

    // one-time load: pair j holds points 2j (x-slot) and 2j+1 (y-slot).
    // x,y -> my private LDS slots; z pinned in registers.
    v2f pz[8], dist[8];
    v2f mx = (v2f){-__builtin_inff(), -__builtin_inff()};
    {
        v2f nq0x = (v2f){-q0x, -q0x}, nq0y = (v2f){-q0y, -q0y}, nq0z = (v2f){-q0z, -q0z};
#pragma unroll
        for (int j = 0; j < 8; j++) {
            v2f px = (v2f){my[6*j  ], my[6*j+3]};
            v2f py = (v2f){my[6*j+1], my[6*j+4]};
            pz[j]  = (v2f){my[6*j+2], my[6*j+5]};
            lds_xp[(j<<10) + t] = px;
            lds_yp[(j<<10) + t] = py;
            dist[j] = pk_d2(px, py, pz[j], nq0x, nq0y, nq0z);  // == min(inf,d2)
            mx = vmax2(mx, dist[j]);
        }
    }
#pragma unroll
    for (int j = 0; j < 8; j++) asm volatile("" : "+v"(pz[j]));

    if (t == 0) {
        ws_sidx[b*GG] = base;                 // selection 0 = index 0
        out[OFF_SIDX + b*GG] = (float)base;
        win[0] = 0xffffffffu; win[1] = 0xffffffffu;
    }
    __syncthreads();

    for (int g = 1; g < GG; g++) {
        const int s = g & 1;
        // ---- per-thread max already fused into previous update (mx)
        float bvf = fmaxf(mx.x, mx.y);
        unsigned lb = __float_as_uint(bvf);   // local max as orderable bits
        // ---- wave max via DPP (value only; result in lane 63)
        unsigned r = lb;
        r = dpp_umax<0x111, 0xf, 0xf>(r);
        r = dpp_umax<0x112, 0xf, 0xf>(r);
        r = dpp_umax<0x114, 0xf, 0xf>(r);
        r = dpp_umax<0x118, 0xf, 0xf>(r);
        r = dpp_umax<0x142, 0xa, 0xf>(r);
        r = dpp_umax<0x143, 0xc, 0xf>(r);
        unsigned wmax = (unsigned)__builtin_amdgcn_readlane((int)r, 63);
        if (lane == 0) wv[wave] = wmax;
        __syncthreads();                      // B1
        if (t == 0) win[1 - s] = 0xffffffffu; // reset other slot for step g+1
        // ---- block max: 16 wave winners, 4-level DPP within rows of 16
        unsigned x = wv[lane & 15];
        x = dpp_umax<0x111, 0xf, 0xf>(x);
        x = dpp_umax<0x112, 0xf, 0xf>(x);
        x = dpp_umax<0x114, 0xf, 0xf>(x);
        x = dpp_umax<0x118, 0xf, 0xf>(x);
        unsigned bmax = (unsigned)__builtin_amdgcn_readlane((int)x, 15);
        // ---- claim: exact first-max index = min p = t*16 + jj (rare path)
        if (lb == bmax) {
            int e = 15;
#pragma unroll
            for (int jj = 15; jj >= 0; jj--) {
                float v = (jj & 1) ? dist[jj >> 1].y : dist[jj >> 1].x;
                if (__float_as_uint(v) == bmax) e = jj;
            }
            atomicMin(&win[s], (unsigned)(t*16 + e));
        }
        __syncthreads();                      // B2: winner resolved
        unsigned pw = win[s];
        int sp = __builtin_amdgcn_readfirstlane((int)pw);
        if (t == 0) {
            ws_sidx[b*GG + g] = base + sp;
            out[OFF_SIDX + b*GG + g] = (float)(base + sp);
        }
        // uniform (scalar) load of winner coords
        float qx = coord[3*(base+sp)];
        float qy = coord[3*(base+sp)+1];
        float qz = coord[3*(base+sp)+2];
        // ---- update: dist = min(dist, |p - q_g|^2), bit-exact, PACKED.
        //      x,y stream from private LDS slots; z from registers.
        v2f nqx = (v2f){-qx, -qx}, nqy = (v2f){-qy, -qy}, nqz = (v2f){-qz, -qz};
        mx = (v2f){-__builtin_inff(), -__builtin_inff()};
#pragma unroll
        for (int j = 0; j < 8; j++) {
            v2f px = lds_xp[(j<<10) + t];
            v2f py = lds_yp[(j<<10) + t];
            v2f d  = pk_d2(px, py, pz[j], nqx, nqy, nqz);
            dist[j] = vmin2(dist[j], d);
            mx = vmax2(mx, dist[j]);
        }
    }
}

// ---------------------------------------------------------------------------
// 2) kNN top-32: one wave per center, no LDS. Per-lane TOP-2 cache of packed
//    keys (mono(d2)<<14 | p): the scattered rescan of the winner's stripe
//    runs only when the winner's cache is empty (~7/32 rounds). mono() makes
//    key order == (d2 float order, index) lex == stable top_k semantics.
// ---------------------------------------------------------------------------
__global__ __launch_bounds__(64) void knn_kernel(const float* __restrict__ coord,
                                                 const int* __restrict__ ws_sidx,
                                                 int* __restrict__ ws_knn) {
#pragma clang fp contract(off)
    const int c = blockIdx.x;             // center 0..8191
    const int l = threadIdx.x;            // lane 0..63
    const int b = c >> 10;
    const int base = b * NN;
    const int sg = ws_sidx[c];            // global center index
    const float cx = coord[3*sg], cy = coord[3*sg+1], cz = coord[3*sg+2];
    const float cc = (cx*cx + cy*cy) + cz*cz;

    // phase 1: per-lane two smallest keys over stripe {l + 64*j}
    uint64_t k1 = ~0ull, k2 = ~0ull;
#pragma unroll 4
    for (int j = 0; j < 256; j++) {
        int p = l + (j << 6);
        float x = coord[3*(base+p)], y = coord[3*(base+p)+1], z = coord[3*(base+p)+2];
        float pp  = (x*x + y*y) + z*z;
        float dot = (cx*x + cy*y) + cz*z;
        float d2  = (cc + pp) - 2.0f*dot;             // ref formula exactly
        uint64_t key = (((uint64_t)mono(d2)) << 14) | (unsigned)p;
        if (key < k1)      { k2 = k1; k1 = key; }
        else if (key < k2) { k2 = key; }
    }

    uint64_t m0 = 0, m1 = 0, m2 = 0, m3 = 0;          // consumed bits, my stripe
    uint64_t cur = k1, nxt = k2;
    bool have_nxt = true;
    int res_p = 0;
    for (int k = 0; k < SS; k++) {
        // global argmin over per-lane current minima (value, then index)
        uint64_t wmin = wave_umin64(cur);
        uint64_t bkey = rdlane64(wmin, 63);           // scalar winner key
        const int bp = (int)(bkey & 16383u);          // winner point (scalar)
        const int w  = bp & 63;                       // winner lane / stripe
        const int e  = bp >> 6;                       // element within stripe
        if (l == k) res_p = bp;                       // lane k keeps k-th neighbor
        bool need_rescan = false;
        if (l == w) {                                 // mark consumed
            uint64_t bit = 1ull << (e & 63);
            int word = e >> 6;
            if      (word == 0) m0 |= bit;
            else if (word == 1) m1 |= bit;
            else if (word == 2) m2 |= bit;
            else                m3 |= bit;
            if (have_nxt) { cur = nxt; have_nxt = false; }
            else need_rescan = true;
        }
        if (__ballot(need_rescan)) {                  // wave-uniform rare path
            uint64_t w0 = rdlane64(m0, w), w1 = rdlane64(m1, w),
                     w2 = rdlane64(m2, w), w3 = rdlane64(m3, w);
            uint64_t best = ~0ull;
#pragma unroll
            for (int m = 0; m < 4; m++) {
                int e2 = l + (m << 6);
                uint64_t mw = (m == 0) ? w0 : ((m == 1) ? w1 : ((m == 2) ? w2 : w3));
                int p2 = w + (e2 << 6);
                float x = coord[3*(base+p2)], y = coord[3*(base+p2)+1], z = coord[3*(base+p2)+2];
                float pp  = (x*x + y*y) + z*z;
                float dot = (cx*x + cy*y) + cz*z;
                float d2  = (cc + pp) - 2.0f*dot;     // bit-exact recompute
                uint64_t key = (((uint64_t)mono(d2)) << 14) | (unsigned)p2;
                bool cons = (mw >> l) & 1ull;
                if (!cons && key < best) best = key;
            }
            best = wave_umin64(best);
            uint64_t rk = rdlane64(best, 63);
            if (l == w) cur = rk;                     // refreshed stripe-min
        }
    }
    if (l < SS) ws_knn[c * SS + l] = res_p;           // local point index
}

// ---------------------------------------------------------------------------
// 3) s_xyz gather
// ---------------------------------------------------------------------------
__global__ void sxyz_kernel(const float* __restrict__ coord,
                            const int* __restrict__ ws_sidx,
                            float* __restrict__ out) {
    int t = blockIdx.x * blockDim.x + threadIdx.x;
    if (t < 8192*3) {
        int i = t / 3, cmp = t - 3*i;
        out[OFF_SXYZ + t] = coord[3*ws_sidx[i] + cmp];
    }
}

// ---------------------------------------------------------------------------
// 4) s_n = coord[knn[1..31]] - center
// ---------------------------------------------------------------------------
__global__ void sn_kernel(const float* __restrict__ coord,
                          const int* __restrict__ ws_sidx,
                          const int* __restrict__ ws_knn,
                          float* __restrict__ out) {
#pragma clang fp contract(off)
    int t = blockIdx.x * blockDim.x + threadIdx.x;
    if (t < 8192*31*3) {
        int cmp = t % 3; int rem = t / 3;
        int j = rem % 31; int i = rem / 31;
        int b = i >> 10;
        int nb = ws_knn[i*SS + j + 1];                // skip neighbor 0 (self)
        int gidx = b*NN + nb;
        float v = coord[3*gidx + cmp] - coord[3*ws_sidx[i] + cmp];
        out[OFF_SN + t] = v;
    }
}

// ---------------------------------------------------------------------------
// 5) stable argsort per code row: REGISTER-BLOCKED bitonic sort of
//    (code<<13 | idx). Thread t owns the 8 contiguous elements i=8t..8t+7 in
//    registers; j>=8 passes swap 64B blocks via LDS. Unique keys => total
//    order == stable argsort (exact).
// ---------------------------------------------------------------------------
__global__ __launch_bounds__(1024) void sort_kernel(const int* __restrict__ ser,
                                                    const int* __restrict__ ws_sidx,
                                                    float* __restrict__ out) {
    __shared__ __align__(16) uint64_t keys[8192];     // 64 KB
    const int r = blockIdx.x, t = threadIdx.x;
    uint64_t e[8];
#pragma unroll
    for (int m = 0; m < 8; m++) {
        int i = t*8 + m;
        uint32_t code = (uint32_t)ser[r * BN + ws_sidx[i]];   // < 2^30
        e[m] = ((uint64_t)code << 13) | (uint32_t)i;          // unique keys
    }
#define CE(a, b, up) { uint64_t xa = e[a], xb = e[b]; \
                       if ((xa > xb) == (up)) { e[a] = xb; e[b] = xa; } }
    // k2 = 2 (up = ((m&2)==0)):
    CE(0,1,true) CE(2,3,false) CE(4,5,true) CE(6,7,false)
    // k2 = 4 (up = ((m&4)==0)):
    CE(0,2,true) CE(1,3,true) CE(4,6,false) CE(5,7,false)
    CE(0,1,true) CE(2,3,true) CE(4,5,false) CE(6,7,false)
    // k2 = 8 (up = ((t&1)==0), uniform in thread):
    {
        bool up = ((t & 1) == 0);
        CE(0,4,up) CE(1,5,up) CE(2,6,up) CE(3,7,up)
        CE(0,2,up) CE(1,3,up) CE(4,6,up) CE(5,7,up)
        CE(0,1,up) CE(2,3,up) CE(4,5,up) CE(6,7,up)
    }
    u64x2* kp = (u64x2*)keys;
    for (int k2 = 16; k2 <= 8192; k2 <<= 1) {
        const bool up = ((t & (k2 >> 3)) == 0);
        for (int j = k2 >> 1; j >= 8; j >>= 1) {
            // publish my current block
#pragma unroll
            for (int q = 0; q < 4; q++)
                kp[t*4 + q] = (u64x2){e[2*q], e[2*q+1]};
            __syncthreads();
            // read partner block (element m pairs with partner's element m)
            const int pt = t ^ (j >> 3);
            uint64_t pb[8];
#pragma unroll
            for (int q = 0; q < 4; q++) {
                u64x2 v = kp[pt*4 + q];
                pb[2*q] = v.x; pb[2*q+1] = v.y;
            }
            const bool lower = ((t & (j >> 3)) == 0);
            const bool keepmin = (lower == up);
#pragma unroll
            for (int m = 0; m < 8; m++) {
                uint64_t a = e[m], bq = pb[m];
                uint64_t mn = a < bq ? a : bq;
                uint64_t mx = a < bq ? bq : a;
                e[m] = keepmin ? mn : mx;
            }
            __syncthreads();   // all reads done before next pass overwrites
        }
        // tail j = 4, 2, 1 in-register (direction up, uniform)
        CE(0,4,up) CE(1,5,up) CE(2,6,up) CE(3,7,up)
        CE(0,2,up) CE(1,3,up) CE(4,6,up) CE(5,7,up)
        CE(0,1,up) CE(2,3,up) CE(4,5,up) CE(6,7,up)
    }
#undef CE
#pragma unroll
    for (int m = 0; m < 8; m++) {
        int k = t*8 + m;
        uint64_t key = e[m];
        int i = (int)(key & 8191u);
        out[OFF_ORD + r*8192 + k] = (float)i;
        out[OFF_INV + r*8192 + i] = (float)k;
    }
}

// ---------------------------------------------------------------------------
extern "C" void kernel_launch(void* const* d_in, const int* in_sizes, int n_in,
                              void* d_out, int out_size, void* d_ws, size_t ws_size,
                              hipStream_t stream) {
    const float* coord = (const float*)d_in[0];
    const int* ser = (const int*)d_in[1];
    float* out = (float*)d_out;
    char* ws = (char*)d_ws;
    int* ws_sidx = (int*)(ws + WS_SIDX);
    int* ws_knn  = (int*)(ws + WS_KNN);

    hipLaunchKernelGGL(fps_kernel,  dim3(BB),   dim3(1024), 0, stream, coord, ws_sidx, out);
    hipLaunchKernelGGL(knn_kernel,  dim3(8192), dim3(64),   0, stream, coord, ws_sidx, ws_knn);
    hipLaunchKernelGGL(sxyz_kernel, dim3(96),   dim3(256),  0, stream, coord, ws_sidx, out);
    hipLaunchKernelGGL(sn_kernel,   dim3(2976), dim3(256),  0, stream, coord, ws_sidx, ws_knn, out);
    hipLaunchKernelGGL(sort_kernel, dim3(4),    dim3(1024), 0, stream, ser, ws_sidx, out);
}